// Round 1
// baseline (689.097 us; speedup 1.0000x reference)
//
#include <hip/hip_runtime.h>
#include <math.h>

#define N_TOKENS 8192
#define DIM      512
#define N_TOOLS  50
#define PARAM_DIM 256

// ---- workspace layout (ints) ----
// [0, 8192)          tool_idx (int)
// [8192, 8256)       counts[64]
// [8256, 8320)       offsets[64]
// [8320, 8384)       cursor[64]
// [8384, 16576)      order[8192]  (token ids grouped by expert)
#define WS_IDX     0
#define WS_COUNTS  8192
#define WS_OFFSETS 8256
#define WS_CURSOR  8320
#define WS_ORDER   8384

// ---------------- router: logits, softmax, argmax, counts ----------------
// one wave (64 threads) per token
__global__ void router_kernel(const float* __restrict__ x,
                              const float* __restrict__ rw,
                              const float* __restrict__ rb,
                              float* __restrict__ out_idx,
                              float* __restrict__ out_probs,
                              int* __restrict__ idx_i,
                              int* __restrict__ counts) {
    int t = blockIdx.x;
    int lane = threadIdx.x;
    const float* xp = x + (size_t)t * DIM;
    float xr[8];
#pragma unroll
    for (int k = 0; k < 8; ++k) xr[k] = xp[lane + 64 * k];

    float my_logit = -INFINITY;
    for (int i = 0; i < N_TOOLS; ++i) {
        const float* w = rw + (size_t)i * DIM;
        float p = 0.f;
#pragma unroll
        for (int k = 0; k < 8; ++k) p += xr[k] * w[lane + 64 * k];
#pragma unroll
        for (int s = 32; s > 0; s >>= 1) p += __shfl_xor(p, s, 64);
        p += rb[i];
        if (lane == i) my_logit = p;
    }

    // softmax over lanes 0..49
    float v = (lane < N_TOOLS) ? my_logit : -INFINITY;
    float m = v;
#pragma unroll
    for (int s = 32; s > 0; s >>= 1) m = fmaxf(m, __shfl_xor(m, s, 64));
    float e = (lane < N_TOOLS) ? expf(v - m) : 0.f;
    float sum = e;
#pragma unroll
    for (int s = 32; s > 0; s >>= 1) sum += __shfl_xor(sum, s, 64);
    if (lane < N_TOOLS) out_probs[(size_t)t * N_TOOLS + lane] = e / sum;

    // argmax with first-index tie-break (matches np.argmax)
    unsigned long long mask = __ballot(v == m);
    int amax = __ffsll((unsigned long long)mask) - 1;
    if (lane == 0) {
        out_idx[t] = (float)amax;
        idx_i[t] = amax;
        atomicAdd(&counts[amax], 1);
    }
}

// ---------------- prefix scan over 50 expert counts ----------------
__global__ void scan_kernel(const int* __restrict__ counts,
                            int* __restrict__ offsets,
                            int* __restrict__ cursor) {
    if (threadIdx.x == 0) {
        int acc = 0;
        for (int i = 0; i < N_TOOLS; ++i) {
            offsets[i] = acc;
            cursor[i] = acc;
            acc += counts[i];
        }
    }
}

// ---------------- scatter tokens into per-expert buckets ----------------
__global__ void scatter_kernel(const int* __restrict__ idx_i,
                               int* __restrict__ cursor,
                               int* __restrict__ order) {
    int t = blockIdx.x * 256 + threadIdx.x;
    int e = idx_i[t];
    int pos = atomicAdd(&cursor[e], 1);
    order[pos] = t;
}

// ---------------- adapted: per-expert bucketed GEMM (fp32) ----------------
// grid (8 col-tiles, 50 experts), block 256. Tiles M=64 tokens, N=64 cols, K=64.
// 4x4 micro-tile per thread.
__global__ void adapted_kernel(const float* __restrict__ x,
                               const float* __restrict__ ew,
                               const float* __restrict__ eb,
                               const int* __restrict__ offsets,
                               const int* __restrict__ counts,
                               const int* __restrict__ order,
                               float* __restrict__ out) {
    int e = blockIdx.y;
    int c0 = blockIdx.x * 64;
    int start = offsets[e];
    int count = counts[e];
    if (count == 0) return;

    __shared__ float As[64][65];   // [row(token)][k]
    __shared__ float Bs[64][65];   // [col][k]
    __shared__ int toks[64];

    int tid = threadIdx.x;
    int tx = tid & 15;   // cols tx*4 .. tx*4+3
    int ty = tid >> 4;   // rows ty*4 .. ty*4+3

    const float* We = ew + (size_t)e * DIM * DIM;
    float bias[4];
#pragma unroll
    for (int j = 0; j < 4; ++j) bias[j] = eb[(size_t)e * DIM + c0 + tx * 4 + j];

    for (int m0 = 0; m0 < count; m0 += 64) {
        __syncthreads();   // protect toks/As/Bs from previous batch readers
        if (tid < 64) toks[tid] = (m0 + tid < count) ? order[start + m0 + tid] : -1;
        __syncthreads();

        float acc[4][4];
#pragma unroll
        for (int i = 0; i < 4; ++i)
#pragma unroll
            for (int j = 0; j < 4; ++j) acc[i][j] = 0.f;

        for (int k0 = 0; k0 < DIM; k0 += 64) {
            // stage A (tokens x k) and B (cols x k); consecutive tid -> consecutive k
#pragma unroll
            for (int i = 0; i < 16; ++i) {
                int idx = i * 256 + tid;
                int k = idx & 63, r = idx >> 6;
                int tok = toks[r];
                As[r][k] = (tok >= 0) ? x[(size_t)tok * DIM + k0 + k] : 0.f;
            }
#pragma unroll
            for (int i = 0; i < 16; ++i) {
                int idx = i * 256 + tid;
                int k = idx & 63, j = idx >> 6;
                Bs[j][k] = We[(size_t)(c0 + j) * DIM + k0 + k];
            }
            __syncthreads();

            for (int kk = 0; kk < 64; ++kk) {
                float a[4], b[4];
#pragma unroll
                for (int i = 0; i < 4; ++i) a[i] = As[ty * 4 + i][kk];
#pragma unroll
                for (int j = 0; j < 4; ++j) b[j] = Bs[tx * 4 + j][kk];
#pragma unroll
                for (int i = 0; i < 4; ++i)
#pragma unroll
                    for (int j = 0; j < 4; ++j) acc[i][j] += a[i] * b[j];
            }
            __syncthreads();
        }

        // writeback
#pragma unroll
        for (int i = 0; i < 4; ++i) {
            int tok = toks[ty * 4 + i];
            if (tok >= 0) {
                float* op = out + (size_t)tok * DIM + c0 + tx * 4;
#pragma unroll
                for (int j = 0; j < 4; ++j) op[j] = acc[i][j] + bias[j];
            }
        }
    }
}

// ---------------- params head: x @ param_w.T + b (fp32 tiled GEMM) ----------------
// grid (4 col-tiles, 128 row-tiles), block 256.
__global__ void params_kernel(const float* __restrict__ x,
                              const float* __restrict__ pw,
                              const float* __restrict__ pb,
                              float* __restrict__ out) {
    int r0 = blockIdx.y * 64;
    int c0 = blockIdx.x * 64;

    __shared__ float As[64][65];
    __shared__ float Bs[64][65];

    int tid = threadIdx.x;
    int tx = tid & 15;
    int ty = tid >> 4;

    float bias[4];
#pragma unroll
    for (int j = 0; j < 4; ++j) bias[j] = pb[c0 + tx * 4 + j];

    float acc[4][4];
#pragma unroll
    for (int i = 0; i < 4; ++i)
#pragma unroll
        for (int j = 0; j < 4; ++j) acc[i][j] = 0.f;

    for (int k0 = 0; k0 < DIM; k0 += 64) {
#pragma unroll
        for (int i = 0; i < 16; ++i) {
            int idx = i * 256 + tid;
            int k = idx & 63, r = idx >> 6;
            As[r][k] = x[(size_t)(r0 + r) * DIM + k0 + k];
        }
#pragma unroll
        for (int i = 0; i < 16; ++i) {
            int idx = i * 256 + tid;
            int k = idx & 63, j = idx >> 6;
            Bs[j][k] = pw[(size_t)(c0 + j) * DIM + k0 + k];
        }
        __syncthreads();

        for (int kk = 0; kk < 64; ++kk) {
            float a[4], b[4];
#pragma unroll
            for (int i = 0; i < 4; ++i) a[i] = As[ty * 4 + i][kk];
#pragma unroll
            for (int j = 0; j < 4; ++j) b[j] = Bs[tx * 4 + j][kk];
#pragma unroll
            for (int i = 0; i < 4; ++i)
#pragma unroll
                for (int j = 0; j < 4; ++j) acc[i][j] += a[i] * b[j];
        }
        __syncthreads();
    }

#pragma unroll
    for (int i = 0; i < 4; ++i) {
        float* op = out + (size_t)(r0 + ty * 4 + i) * PARAM_DIM + c0 + tx * 4;
#pragma unroll
        for (int j = 0; j < 4; ++j) op[j] = acc[i][j] + bias[j];
    }
}

extern "C" void kernel_launch(void* const* d_in, const int* in_sizes, int n_in,
                              void* d_out, int out_size, void* d_ws, size_t ws_size,
                              hipStream_t stream) {
    const float* x        = (const float*)d_in[0];
    const float* router_w = (const float*)d_in[1];
    const float* router_b = (const float*)d_in[2];
    const float* expert_w = (const float*)d_in[3];
    const float* expert_b = (const float*)d_in[4];
    const float* param_w  = (const float*)d_in[5];
    const float* param_b  = (const float*)d_in[6];

    float* out = (float*)d_out;
    float* out_idx     = out;                                  // 8192
    float* out_probs   = out + N_TOKENS;                       // 409600
    float* out_adapted = out + N_TOKENS + N_TOKENS * N_TOOLS;  // 4194304
    float* out_params  = out_adapted + (size_t)N_TOKENS * DIM; // 2097152

    int* ws = (int*)d_ws;
    int* ws_idx     = ws + WS_IDX;
    int* ws_counts  = ws + WS_COUNTS;
    int* ws_offsets = ws + WS_OFFSETS;
    int* ws_cursor  = ws + WS_CURSOR;
    int* ws_order   = ws + WS_ORDER;

    // zero expert counts (ws is poisoned 0xAA before every timed launch)
    hipMemsetAsync(ws_counts, 0, 64 * sizeof(int), stream);

    router_kernel<<<N_TOKENS, 64, 0, stream>>>(x, router_w, router_b,
                                               out_idx, out_probs, ws_idx, ws_counts);

    scan_kernel<<<1, 64, 0, stream>>>(ws_counts, ws_offsets, ws_cursor);

    scatter_kernel<<<N_TOKENS / 256, 256, 0, stream>>>(ws_idx, ws_cursor, ws_order);

    adapted_kernel<<<dim3(8, 50), 256, 0, stream>>>(x, expert_w, expert_b,
                                                    ws_offsets, ws_counts, ws_order,
                                                    out_adapted);

    params_kernel<<<dim3(4, 128), 256, 0, stream>>>(x, param_w, param_b, out_params);
}

// Round 2
// 318.764 us; speedup vs baseline: 2.1618x; 2.1618x over previous
//
#include <hip/hip_runtime.h>
#include <math.h>

#define N_TOKENS 8192
#define DIM      512
#define N_TOOLS  50
#define PARAM_DIM 256
#define MAX_BATCHES 192
#define LDSS 72   // LDS inner stride in bf16 elems (144 B = 36 banks -> 2-way max, free)

typedef float  f32x4 __attribute__((ext_vector_type(4)));
typedef short  s16x8 __attribute__((ext_vector_type(8)));
typedef short  s16x4 __attribute__((ext_vector_type(4)));

// ---- workspace layout (ints) ----
#define WS_IDX     0        // 8192
#define WS_COUNTS  8192     // 64
#define WS_OFFSETS 8256     // 64
#define WS_CURSOR  8320     // 64
#define WS_ORDER   8384     // 8192
#define WS_BE      16576    // 192 batch -> expert
#define WS_BM0     16768    // 192 batch -> m0 within expert
#define WS_NB      16960    // 1

__device__ inline short f2bf(float f) {
    unsigned u = __float_as_uint(f);
    u += 0x7fff + ((u >> 16) & 1);   // round-to-nearest-even
    return (short)(u >> 16);
}

// ---------------- router logits: fp32 tiled GEMM, logits -> out_probs slot ----------------
// grid (1, 128), block 256. Tile M=64, N=64 (50 valid), K=64 steps.
__global__ __launch_bounds__(256) void logits_kernel(const float* __restrict__ x,
                                                     const float* __restrict__ rw,
                                                     const float* __restrict__ rb,
                                                     float* __restrict__ logits) {
    int r0 = blockIdx.y * 64;

    __shared__ float As[64][65];
    __shared__ float Bs[64][65];

    int tid = threadIdx.x;
    int tx = tid & 15;
    int ty = tid >> 4;

    float acc[4][4];
#pragma unroll
    for (int i = 0; i < 4; ++i)
#pragma unroll
        for (int j = 0; j < 4; ++j) acc[i][j] = 0.f;

    for (int k0 = 0; k0 < DIM; k0 += 64) {
#pragma unroll
        for (int i = 0; i < 16; ++i) {
            int idx = i * 256 + tid;
            int k = idx & 63, r = idx >> 6;
            As[r][k] = x[(size_t)(r0 + r) * DIM + k0 + k];
        }
#pragma unroll
        for (int i = 0; i < 16; ++i) {
            int idx = i * 256 + tid;
            int k = idx & 63, j = idx >> 6;
            Bs[j][k] = (j < N_TOOLS) ? rw[(size_t)j * DIM + k0 + k] : 0.f;
        }
        __syncthreads();

        for (int kk = 0; kk < 64; ++kk) {
            float a[4], b[4];
#pragma unroll
            for (int i = 0; i < 4; ++i) a[i] = As[ty * 4 + i][kk];
#pragma unroll
            for (int j = 0; j < 4; ++j) b[j] = Bs[tx * 4 + j][kk];
#pragma unroll
            for (int i = 0; i < 4; ++i)
#pragma unroll
                for (int j = 0; j < 4; ++j) acc[i][j] += a[i] * b[j];
        }
        __syncthreads();
    }

#pragma unroll
    for (int i = 0; i < 4; ++i) {
#pragma unroll
        for (int j = 0; j < 4; ++j) {
            int c = tx * 4 + j;
            if (c < N_TOOLS)
                logits[(size_t)(r0 + ty * 4 + i) * N_TOOLS + c] = acc[i][j] + rb[c];
        }
    }
}

// ---------------- softmax / argmax / counts (reads+rewrites probs in place) ----------------
__global__ void softmax_kernel(float* __restrict__ probs,
                               float* __restrict__ out_idx,
                               int* __restrict__ idx_i,
                               int* __restrict__ counts) {
    int t = blockIdx.x * 4 + (threadIdx.x >> 6);
    int lane = threadIdx.x & 63;
    float v = (lane < N_TOOLS) ? probs[(size_t)t * N_TOOLS + lane] : -INFINITY;
    float m = v;
#pragma unroll
    for (int s = 32; s > 0; s >>= 1) m = fmaxf(m, __shfl_xor(m, s, 64));
    float e = (lane < N_TOOLS) ? expf(v - m) : 0.f;
    float sum = e;
#pragma unroll
    for (int s = 32; s > 0; s >>= 1) sum += __shfl_xor(sum, s, 64);
    unsigned long long mask = __ballot(v == m);
    int amax = __ffsll((unsigned long long)mask) - 1;
    if (lane < N_TOOLS) probs[(size_t)t * N_TOOLS + lane] = e / sum;
    if (lane == 0) {
        out_idx[t] = (float)amax;
        idx_i[t] = amax;
        atomicAdd(&counts[amax], 1);
    }
}

// ---------------- scan + batch table ----------------
__global__ void scan_kernel(const int* __restrict__ counts,
                            int* __restrict__ offsets,
                            int* __restrict__ cursor,
                            int* __restrict__ batch_e,
                            int* __restrict__ batch_m0,
                            int* __restrict__ nb_out) {
    if (threadIdx.x == 0) {
        int acc = 0, nb = 0;
        for (int i = 0; i < N_TOOLS; ++i) {
            offsets[i] = acc;
            cursor[i] = acc;
            int c = counts[i];
            acc += c;
            for (int m0 = 0; m0 < c; m0 += 64) {
                batch_e[nb] = i;
                batch_m0[nb] = m0;
                ++nb;
            }
        }
        nb_out[0] = nb;
    }
}

// ---------------- scatter tokens into per-expert buckets ----------------
__global__ void scatter_kernel(const int* __restrict__ idx_i,
                               int* __restrict__ cursor,
                               int* __restrict__ order) {
    int t = blockIdx.x * 256 + threadIdx.x;
    int e = idx_i[t];
    int pos = atomicAdd(&cursor[e], 1);
    order[pos] = t;
}

// ---------------- adapted: grouped bf16 MFMA GEMM ----------------
// grid (8 col-tiles, MAX_BATCHES), block 256 (4 waves). Tile 64x64, BK=64.
// Wave w computes rows [w*16, w*16+16) x 64 cols via 4x mfma_f32_16x16x32_bf16.
__global__ __launch_bounds__(256) void adapted_mfma(const float* __restrict__ x,
                                                    const float* __restrict__ ew,
                                                    const float* __restrict__ eb,
                                                    const int* __restrict__ order,
                                                    const int* __restrict__ batch_e,
                                                    const int* __restrict__ batch_m0,
                                                    const int* __restrict__ nb_ptr,
                                                    const int* __restrict__ offsets,
                                                    const int* __restrict__ counts,
                                                    float* __restrict__ out) {
    int b = blockIdx.y;
    if (b >= nb_ptr[0]) return;
    int e = batch_e[b];
    int m0 = batch_m0[b];
    int c0 = blockIdx.x * 64;
    int start = offsets[e] + m0;
    int len = counts[e] - m0;
    if (len > 64) len = 64;

    __shared__ short As[64 * LDSS];
    __shared__ short Bs[64 * LDSS];
    __shared__ int toks[64];

    int tid = threadIdx.x;
    if (tid < 64) toks[tid] = (tid < len) ? order[start + tid] : -1;
    __syncthreads();

    int wv = tid >> 6;
    int lane = tid & 63;
    int fm = lane & 15;      // fragment row/col index
    int q = lane >> 4;       // quad

    const float* We = ew + (size_t)e * DIM * DIM;

    f32x4 acc[4] = {{0.f, 0.f, 0.f, 0.f}, {0.f, 0.f, 0.f, 0.f},
                    {0.f, 0.f, 0.f, 0.f}, {0.f, 0.f, 0.f, 0.f}};

    for (int k0 = 0; k0 < DIM; k0 += 64) {
        // stage A: 64 token-rows x 64 k (fp32 -> bf16)
#pragma unroll
        for (int i = 0; i < 4; ++i) {
            int u = i * 256 + tid;
            int r = u >> 4, g = u & 15;
            int tok = toks[r];
            float4 v = {0.f, 0.f, 0.f, 0.f};
            if (tok >= 0) v = *(const float4*)&x[(size_t)tok * DIM + k0 + g * 4];
            s16x4 h = {f2bf(v.x), f2bf(v.y), f2bf(v.z), f2bf(v.w)};
            *(s16x4*)&As[r * LDSS + g * 4] = h;
        }
        // stage B: 64 cols x 64 k from W[c][k]
#pragma unroll
        for (int i = 0; i < 4; ++i) {
            int u = i * 256 + tid;
            int c = u >> 4, g = u & 15;
            float4 v = *(const float4*)&We[(size_t)(c0 + c) * DIM + k0 + g * 4];
            s16x4 h = {f2bf(v.x), f2bf(v.y), f2bf(v.z), f2bf(v.w)};
            *(s16x4*)&Bs[c * LDSS + g * 4] = h;
        }
        __syncthreads();

#pragma unroll
        for (int kk = 0; kk < 64; kk += 32) {
            s16x8 a = *(const s16x8*)&As[(wv * 16 + fm) * LDSS + kk + q * 8];
#pragma unroll
            for (int n = 0; n < 4; ++n) {
                s16x8 bf = *(const s16x8*)&Bs[(n * 16 + fm) * LDSS + kk + q * 8];
                acc[n] = __builtin_amdgcn_mfma_f32_16x16x32_bf16(a, bf, acc[n], 0, 0, 0);
            }
        }
        __syncthreads();
    }

    // epilogue: D layout col=lane&15, row=(lane>>4)*4+reg
    float bias[4];
#pragma unroll
    for (int n = 0; n < 4; ++n) bias[n] = eb[(size_t)e * DIM + c0 + n * 16 + fm];

#pragma unroll
    for (int r = 0; r < 4; ++r) {
        int row = wv * 16 + q * 4 + r;
        int tok = toks[row];
        if (tok < 0) continue;
        float* op = out + (size_t)tok * DIM + c0;
#pragma unroll
        for (int n = 0; n < 4; ++n) op[n * 16 + fm] = acc[n][r] + bias[n];
    }
}

// ---------------- params: bf16 MFMA GEMM, M=8192 N=256 K=512 ----------------
// grid (4, 128), block 256.
__global__ __launch_bounds__(256) void params_mfma(const float* __restrict__ x,
                                                   const float* __restrict__ pw,
                                                   const float* __restrict__ pb,
                                                   float* __restrict__ out) {
    int r0 = blockIdx.y * 64;
    int c0 = blockIdx.x * 64;

    __shared__ short As[64 * LDSS];
    __shared__ short Bs[64 * LDSS];

    int tid = threadIdx.x;
    int wv = tid >> 6;
    int lane = tid & 63;
    int fm = lane & 15;
    int q = lane >> 4;

    f32x4 acc[4] = {{0.f, 0.f, 0.f, 0.f}, {0.f, 0.f, 0.f, 0.f},
                    {0.f, 0.f, 0.f, 0.f}, {0.f, 0.f, 0.f, 0.f}};

    for (int k0 = 0; k0 < DIM; k0 += 64) {
#pragma unroll
        for (int i = 0; i < 4; ++i) {
            int u = i * 256 + tid;
            int r = u >> 4, g = u & 15;
            float4 v = *(const float4*)&x[(size_t)(r0 + r) * DIM + k0 + g * 4];
            s16x4 h = {f2bf(v.x), f2bf(v.y), f2bf(v.z), f2bf(v.w)};
            *(s16x4*)&As[r * LDSS + g * 4] = h;
        }
#pragma unroll
        for (int i = 0; i < 4; ++i) {
            int u = i * 256 + tid;
            int c = u >> 4, g = u & 15;
            float4 v = *(const float4*)&pw[(size_t)(c0 + c) * DIM + k0 + g * 4];
            s16x4 h = {f2bf(v.x), f2bf(v.y), f2bf(v.z), f2bf(v.w)};
            *(s16x4*)&Bs[c * LDSS + g * 4] = h;
        }
        __syncthreads();

#pragma unroll
        for (int kk = 0; kk < 64; kk += 32) {
            s16x8 a = *(const s16x8*)&As[(wv * 16 + fm) * LDSS + kk + q * 8];
#pragma unroll
            for (int n = 0; n < 4; ++n) {
                s16x8 bf = *(const s16x8*)&Bs[(n * 16 + fm) * LDSS + kk + q * 8];
                acc[n] = __builtin_amdgcn_mfma_f32_16x16x32_bf16(a, bf, acc[n], 0, 0, 0);
            }
        }
        __syncthreads();
    }

    float bias[4];
#pragma unroll
    for (int n = 0; n < 4; ++n) bias[n] = pb[c0 + n * 16 + fm];

#pragma unroll
    for (int r = 0; r < 4; ++r) {
        int row = r0 + wv * 16 + q * 4 + r;
        float* op = out + (size_t)row * PARAM_DIM + c0;
#pragma unroll
        for (int n = 0; n < 4; ++n) op[n * 16 + fm] = acc[n][r] + bias[n];
    }
}

extern "C" void kernel_launch(void* const* d_in, const int* in_sizes, int n_in,
                              void* d_out, int out_size, void* d_ws, size_t ws_size,
                              hipStream_t stream) {
    const float* x        = (const float*)d_in[0];
    const float* router_w = (const float*)d_in[1];
    const float* router_b = (const float*)d_in[2];
    const float* expert_w = (const float*)d_in[3];
    const float* expert_b = (const float*)d_in[4];
    const float* param_w  = (const float*)d_in[5];
    const float* param_b  = (const float*)d_in[6];

    float* out = (float*)d_out;
    float* out_idx     = out;                                  // 8192
    float* out_probs   = out + N_TOKENS;                       // 409600 (used as logits scratch first)
    float* out_adapted = out + N_TOKENS + N_TOKENS * N_TOOLS;  // 4194304
    float* out_params  = out_adapted + (size_t)N_TOKENS * DIM; // 2097152

    int* ws = (int*)d_ws;
    int* ws_idx     = ws + WS_IDX;
    int* ws_counts  = ws + WS_COUNTS;
    int* ws_offsets = ws + WS_OFFSETS;
    int* ws_cursor  = ws + WS_CURSOR;
    int* ws_order   = ws + WS_ORDER;
    int* ws_be      = ws + WS_BE;
    int* ws_bm0     = ws + WS_BM0;
    int* ws_nb      = ws + WS_NB;

    hipMemsetAsync(ws_counts, 0, 64 * sizeof(int), stream);

    logits_kernel<<<dim3(1, N_TOKENS / 64), 256, 0, stream>>>(x, router_w, router_b, out_probs);

    softmax_kernel<<<N_TOKENS / 4, 256, 0, stream>>>(out_probs, out_idx, ws_idx, ws_counts);

    scan_kernel<<<1, 64, 0, stream>>>(ws_counts, ws_offsets, ws_cursor, ws_be, ws_bm0, ws_nb);

    scatter_kernel<<<N_TOKENS / 256, 256, 0, stream>>>(ws_idx, ws_cursor, ws_order);

    adapted_mfma<<<dim3(8, MAX_BATCHES), 256, 0, stream>>>(x, expert_w, expert_b,
                                                           ws_order, ws_be, ws_bm0, ws_nb,
                                                           ws_offsets, ws_counts, out_adapted);

    params_mfma<<<dim3(4, 128), 256, 0, stream>>>(x, param_w, param_b, out_params);
}

// Round 3
// 219.358 us; speedup vs baseline: 3.1414x; 1.4532x over previous
//
#include <hip/hip_runtime.h>
#include <hip/hip_bf16.h>
#include <math.h>

#define N_TOKENS 8192
#define DIM      512
#define N_TOOLS  50
#define PARAM_DIM 256
#define MAX_BATCHES 192
#define LDSS 72   // LDS inner stride in bf16 elems (144 B -> 2-way bank aliasing max, free)

typedef float  f32x4 __attribute__((ext_vector_type(4)));
typedef short  s16x8 __attribute__((ext_vector_type(8)));
typedef short  s16x4 __attribute__((ext_vector_type(4)));

// ---- workspace layout (ints) ----
#define WS_IDX     0        // 8192
#define WS_COUNTS  8192     // 64
#define WS_OFFSETS 8256     // 64
#define WS_CURSOR  8320     // 64
#define WS_ORDER   8384     // 8192
#define WS_BE      16576    // 192
#define WS_BM0     16768    // 192
#define WS_NB      16960    // 1

__device__ inline float bf2f(short s) {
    return __uint_as_float(((unsigned)(unsigned short)s) << 16);
}

__device__ inline s16x4 pk4(float a, float b, float c, float d) {
    __hip_bfloat162 p0 = __float22bfloat162_rn(make_float2(a, b));
    __hip_bfloat162 p1 = __float22bfloat162_rn(make_float2(c, d));
    union { __hip_bfloat162 h; short2 s; } u0, u1;
    u0.h = p0; u1.h = p1;
    s16x4 r; r[0] = u0.s.x; r[1] = u0.s.y; r[2] = u1.s.x; r[3] = u1.s.y;
    return r;
}

// ---------------- fused head: params (tiles 0-3) + logits (tile 4, split-bf16) ----------------
// grid (5, 128), block 256 (4 waves). Tile 64x64, BK=64.
// Logits tile uses 2-term decomposition x=hi+lo, w=hi+lo; acc += hi*whi + hi*wlo + lo*whi
// -> ~fp32 accuracy so argmax/softmax match the fp32 reference.
__global__ __launch_bounds__(256) void head_mfma(const float* __restrict__ x,
                                                 const float* __restrict__ pw,
                                                 const float* __restrict__ pb,
                                                 const float* __restrict__ rw,
                                                 const float* __restrict__ rb,
                                                 float* __restrict__ out_params,
                                                 float* __restrict__ logits) {
    int r0 = blockIdx.y * 64;
    bool isl = (blockIdx.x == 4);
    int c0 = isl ? 0 : blockIdx.x * 64;

    __shared__ short As[64 * LDSS];
    __shared__ short Bs[64 * LDSS];
    __shared__ short Al[64 * LDSS];   // lo parts, used by logits tile only
    __shared__ short Bl[64 * LDSS];

    int tid = threadIdx.x;
    int wv = tid >> 6;
    int lane = tid & 63;
    int fm = lane & 15;
    int q = lane >> 4;

    const float* Bsrc = isl ? rw : pw;

    f32x4 acc[4] = {{0.f, 0.f, 0.f, 0.f}, {0.f, 0.f, 0.f, 0.f},
                    {0.f, 0.f, 0.f, 0.f}, {0.f, 0.f, 0.f, 0.f}};

    for (int k0 = 0; k0 < DIM; k0 += 64) {
        // stage A (64 rows x 64 k)
#pragma unroll
        for (int i = 0; i < 4; ++i) {
            int u = i * 256 + tid;
            int r = u >> 4, g = u & 15;
            float4 v = *(const float4*)&x[(size_t)(r0 + r) * DIM + k0 + g * 4];
            s16x4 h = pk4(v.x, v.y, v.z, v.w);
            *(s16x4*)&As[r * LDSS + g * 4] = h;
            if (isl) {
                s16x4 l = pk4(v.x - bf2f(h[0]), v.y - bf2f(h[1]),
                              v.z - bf2f(h[2]), v.w - bf2f(h[3]));
                *(s16x4*)&Al[r * LDSS + g * 4] = l;
            }
        }
        // stage B (64 cols x 64 k)
#pragma unroll
        for (int i = 0; i < 4; ++i) {
            int u = i * 256 + tid;
            int c = u >> 4, g = u & 15;
            float4 v = {0.f, 0.f, 0.f, 0.f};
            if (!isl || c < N_TOOLS)
                v = *(const float4*)&Bsrc[(size_t)(c0 + c) * DIM + k0 + g * 4];
            s16x4 h = pk4(v.x, v.y, v.z, v.w);
            *(s16x4*)&Bs[c * LDSS + g * 4] = h;
            if (isl) {
                s16x4 l = pk4(v.x - bf2f(h[0]), v.y - bf2f(h[1]),
                              v.z - bf2f(h[2]), v.w - bf2f(h[3]));
                *(s16x4*)&Bl[c * LDSS + g * 4] = l;
            }
        }
        __syncthreads();

#pragma unroll
        for (int kk = 0; kk < 64; kk += 32) {
            int ao = (wv * 16 + fm) * LDSS + kk + q * 8;
            s16x8 a = *(const s16x8*)&As[ao];
            if (!isl) {
#pragma unroll
                for (int n = 0; n < 4; ++n) {
                    s16x8 b = *(const s16x8*)&Bs[(n * 16 + fm) * LDSS + kk + q * 8];
                    acc[n] = __builtin_amdgcn_mfma_f32_16x16x32_bf16(a, b, acc[n], 0, 0, 0);
                }
            } else {
                s16x8 al = *(const s16x8*)&Al[ao];
#pragma unroll
                for (int n = 0; n < 4; ++n) {
                    int bo = (n * 16 + fm) * LDSS + kk + q * 8;
                    s16x8 b  = *(const s16x8*)&Bs[bo];
                    s16x8 bl = *(const s16x8*)&Bl[bo];
                    acc[n] = __builtin_amdgcn_mfma_f32_16x16x32_bf16(a,  b,  acc[n], 0, 0, 0);
                    acc[n] = __builtin_amdgcn_mfma_f32_16x16x32_bf16(a,  bl, acc[n], 0, 0, 0);
                    acc[n] = __builtin_amdgcn_mfma_f32_16x16x32_bf16(al, b,  acc[n], 0, 0, 0);
                }
            }
        }
        __syncthreads();
    }

    // epilogue: D layout col=lane&15 (per n-frag), row=q*4+r
    if (!isl) {
        float bias[4];
#pragma unroll
        for (int n = 0; n < 4; ++n) bias[n] = pb[c0 + n * 16 + fm];
#pragma unroll
        for (int r = 0; r < 4; ++r) {
            int row = r0 + wv * 16 + q * 4 + r;
            float* op = out_params + (size_t)row * PARAM_DIM + c0;
#pragma unroll
            for (int n = 0; n < 4; ++n) op[n * 16 + fm] = acc[n][r] + bias[n];
        }
    } else {
#pragma unroll
        for (int r = 0; r < 4; ++r) {
            int row = r0 + wv * 16 + q * 4 + r;
#pragma unroll
            for (int n = 0; n < 4; ++n) {
                int c = n * 16 + fm;
                if (c < N_TOOLS)
                    logits[(size_t)row * N_TOOLS + c] = acc[n][r] + rb[c];
            }
        }
    }
}

// ---------------- softmax / argmax / counts (in-place over logits->probs) ----------------
__global__ void softmax_kernel(float* __restrict__ probs,
                               float* __restrict__ out_idx,
                               int* __restrict__ idx_i,
                               int* __restrict__ counts) {
    int t = blockIdx.x * 4 + (threadIdx.x >> 6);
    int lane = threadIdx.x & 63;
    float v = (lane < N_TOOLS) ? probs[(size_t)t * N_TOOLS + lane] : -INFINITY;
    float m = v;
#pragma unroll
    for (int s = 32; s > 0; s >>= 1) m = fmaxf(m, __shfl_xor(m, s, 64));
    float e = (lane < N_TOOLS) ? expf(v - m) : 0.f;
    float sum = e;
#pragma unroll
    for (int s = 32; s > 0; s >>= 1) sum += __shfl_xor(sum, s, 64);
    unsigned long long mask = __ballot(v == m);
    int amax = __ffsll((unsigned long long)mask) - 1;
    if (lane < N_TOOLS) probs[(size_t)t * N_TOOLS + lane] = e / sum;
    if (lane == 0) {
        out_idx[t] = (float)amax;
        idx_i[t] = amax;
        atomicAdd(&counts[amax], 1);
    }
}

// ---------------- wave-parallel scan + batch table ----------------
__global__ void scan_kernel(const int* __restrict__ counts,
                            int* __restrict__ offsets,
                            int* __restrict__ cursor,
                            int* __restrict__ batch_e,
                            int* __restrict__ batch_m0,
                            int* __restrict__ nb_out) {
    int lane = threadIdx.x;   // 64
    int c = (lane < N_TOOLS) ? counts[lane] : 0;
    int pre = c;
#pragma unroll
    for (int s = 1; s < 64; s <<= 1) {
        int v = __shfl_up(pre, s, 64);
        if (lane >= s) pre += v;
    }
    int excl = pre - c;
    if (lane < N_TOOLS) { offsets[lane] = excl; cursor[lane] = excl; }

    int nb_i = (lane < N_TOOLS) ? (c + 63) >> 6 : 0;
    int pre2 = nb_i;
#pragma unroll
    for (int s = 1; s < 64; s <<= 1) {
        int v = __shfl_up(pre2, s, 64);
        if (lane >= s) pre2 += v;
    }
    int bstart = pre2 - nb_i;
    for (int b = 0; b < nb_i; ++b) {
        batch_e[bstart + b] = lane;
        batch_m0[bstart + b] = b * 64;
    }
    if (lane == 63) nb_out[0] = pre2;
}

// ---------------- scatter tokens into per-expert buckets ----------------
__global__ void scatter_kernel(const int* __restrict__ idx_i,
                               int* __restrict__ cursor,
                               int* __restrict__ order) {
    int t = blockIdx.x * 256 + threadIdx.x;
    int e = idx_i[t];
    int pos = atomicAdd(&cursor[e], 1);
    order[pos] = t;
}

// ---------------- adapted: grouped bf16 MFMA GEMM ----------------
// grid (8 col-tiles, MAX_BATCHES), block 256 (4 waves). Tile 64x64, BK=64.
__global__ __launch_bounds__(256) void adapted_mfma(const float* __restrict__ x,
                                                    const float* __restrict__ ew,
                                                    const float* __restrict__ eb,
                                                    const int* __restrict__ order,
                                                    const int* __restrict__ batch_e,
                                                    const int* __restrict__ batch_m0,
                                                    const int* __restrict__ nb_ptr,
                                                    const int* __restrict__ offsets,
                                                    const int* __restrict__ counts,
                                                    float* __restrict__ out) {
    int b = blockIdx.y;
    if (b >= nb_ptr[0]) return;
    int e = batch_e[b];
    int m0 = batch_m0[b];
    int c0 = blockIdx.x * 64;
    int start = offsets[e] + m0;
    int len = counts[e] - m0;
    if (len > 64) len = 64;

    __shared__ short As[64 * LDSS];
    __shared__ short Bs[64 * LDSS];
    __shared__ int toks[64];

    int tid = threadIdx.x;
    if (tid < 64) toks[tid] = (tid < len) ? order[start + tid] : -1;
    __syncthreads();

    int wv = tid >> 6;
    int lane = tid & 63;
    int fm = lane & 15;
    int q = lane >> 4;

    const float* We = ew + (size_t)e * DIM * DIM;

    f32x4 acc[4] = {{0.f, 0.f, 0.f, 0.f}, {0.f, 0.f, 0.f, 0.f},
                    {0.f, 0.f, 0.f, 0.f}, {0.f, 0.f, 0.f, 0.f}};

    for (int k0 = 0; k0 < DIM; k0 += 64) {
#pragma unroll
        for (int i = 0; i < 4; ++i) {
            int u = i * 256 + tid;
            int r = u >> 4, g = u & 15;
            int tok = toks[r];
            float4 v = {0.f, 0.f, 0.f, 0.f};
            if (tok >= 0) v = *(const float4*)&x[(size_t)tok * DIM + k0 + g * 4];
            *(s16x4*)&As[r * LDSS + g * 4] = pk4(v.x, v.y, v.z, v.w);
        }
#pragma unroll
        for (int i = 0; i < 4; ++i) {
            int u = i * 256 + tid;
            int c = u >> 4, g = u & 15;
            float4 v = *(const float4*)&We[(size_t)(c0 + c) * DIM + k0 + g * 4];
            *(s16x4*)&Bs[c * LDSS + g * 4] = pk4(v.x, v.y, v.z, v.w);
        }
        __syncthreads();

#pragma unroll
        for (int kk = 0; kk < 64; kk += 32) {
            s16x8 a = *(const s16x8*)&As[(wv * 16 + fm) * LDSS + kk + q * 8];
#pragma unroll
            for (int n = 0; n < 4; ++n) {
                s16x8 bf = *(const s16x8*)&Bs[(n * 16 + fm) * LDSS + kk + q * 8];
                acc[n] = __builtin_amdgcn_mfma_f32_16x16x32_bf16(a, bf, acc[n], 0, 0, 0);
            }
        }
        __syncthreads();
    }

    float bias[4];
#pragma unroll
    for (int n = 0; n < 4; ++n) bias[n] = eb[(size_t)e * DIM + c0 + n * 16 + fm];

#pragma unroll
    for (int r = 0; r < 4; ++r) {
        int row = wv * 16 + q * 4 + r;
        int tok = toks[row];
        if (tok < 0) continue;
        float* op = out + (size_t)tok * DIM + c0;
#pragma unroll
        for (int n = 0; n < 4; ++n) op[n * 16 + fm] = acc[n][r] + bias[n];
    }
}

extern "C" void kernel_launch(void* const* d_in, const int* in_sizes, int n_in,
                              void* d_out, int out_size, void* d_ws, size_t ws_size,
                              hipStream_t stream) {
    const float* x        = (const float*)d_in[0];
    const float* router_w = (const float*)d_in[1];
    const float* router_b = (const float*)d_in[2];
    const float* expert_w = (const float*)d_in[3];
    const float* expert_b = (const float*)d_in[4];
    const float* param_w  = (const float*)d_in[5];
    const float* param_b  = (const float*)d_in[6];

    float* out = (float*)d_out;
    float* out_idx     = out;                                  // 8192
    float* out_probs   = out + N_TOKENS;                       // 409600 (logits scratch first)
    float* out_adapted = out + N_TOKENS + N_TOKENS * N_TOOLS;  // 4194304
    float* out_params  = out_adapted + (size_t)N_TOKENS * DIM; // 2097152

    int* ws = (int*)d_ws;
    int* ws_idx     = ws + WS_IDX;
    int* ws_counts  = ws + WS_COUNTS;
    int* ws_offsets = ws + WS_OFFSETS;
    int* ws_cursor  = ws + WS_CURSOR;
    int* ws_order   = ws + WS_ORDER;
    int* ws_be      = ws + WS_BE;
    int* ws_bm0     = ws + WS_BM0;
    int* ws_nb      = ws + WS_NB;

    hipMemsetAsync(ws_counts, 0, 64 * sizeof(int), stream);

    head_mfma<<<dim3(5, N_TOKENS / 64), 256, 0, stream>>>(x, param_w, param_b,
                                                          router_w, router_b,
                                                          out_params, out_probs);

    softmax_kernel<<<N_TOKENS / 4, 256, 0, stream>>>(out_probs, out_idx, ws_idx, ws_counts);

    scan_kernel<<<1, 64, 0, stream>>>(ws_counts, ws_offsets, ws_cursor, ws_be, ws_bm0, ws_nb);

    scatter_kernel<<<N_TOKENS / 256, 256, 0, stream>>>(ws_idx, ws_cursor, ws_order);

    adapted_mfma<<<dim3(8, MAX_BATCHES), 256, 0, stream>>>(x, expert_w, expert_b,
                                                           ws_order, ws_be, ws_bm0, ws_nb,
                                                           ws_offsets, ws_counts, out_adapted);
}

// Round 4
// 176.681 us; speedup vs baseline: 3.9002x; 1.2415x over previous
//
#include <hip/hip_runtime.h>
#include <hip/hip_bf16.h>
#include <math.h>

#define N_TOKENS 8192
#define DIM      512
#define N_TOOLS  50
#define PARAM_DIM 256
#define N_ROWBLK (N_TOKENS / 64)   // 128
#define MAX_BATCHES 192
#define LDSS 72   // LDS inner stride in bf16 elems (144 B -> 2-way bank aliasing max, free)

typedef float  f32x4 __attribute__((ext_vector_type(4)));
typedef short  s16x8 __attribute__((ext_vector_type(8)));
typedef short  s16x4 __attribute__((ext_vector_type(4)));

// ---- workspace layout (ints) ----
#define WS_IDX     0        // 8192  token -> expert
#define WS_HIST    8192     // 128*50 per-rowblock histograms
#define WS_PHIST   14592    // 128*50 exclusive block-prefix per expert
#define WS_OFFSETS 20992    // 64
#define WS_COUNTS  21056    // 64
#define WS_ORDER   21120    // 8192
#define WS_BE      29312    // 192
#define WS_BM0     29504    // 192
#define WS_NB      29696    // 1

__device__ inline float bf2f(short s) {
    return __uint_as_float(((unsigned)(unsigned short)s) << 16);
}

__device__ inline s16x4 pk4(float a, float b, float c, float d) {
    __hip_bfloat162 p0 = __float22bfloat162_rn(make_float2(a, b));
    __hip_bfloat162 p1 = __float22bfloat162_rn(make_float2(c, d));
    union { __hip_bfloat162 h; short2 s; } u0, u1;
    u0.h = p0; u1.h = p1;
    s16x4 r; r[0] = u0.s.x; r[1] = u0.s.y; r[2] = u1.s.x; r[3] = u1.s.y;
    return r;
}

// ---------------- fused head: params (tiles 0-3) + logits/softmax/argmax (tile 4) ----------------
// grid (5, 128), block 256 (4 waves). Tile 64x64, BK=64.
// Logits tile: split-bf16 (x=hi+lo, w=hi+lo; 3 MFMAs) -> ~fp32 logits, then in-register
// softmax + first-index argmax + per-block expert histogram (no atomics anywhere).
__global__ __launch_bounds__(256) void head_mfma(const float* __restrict__ x,
                                                 const float* __restrict__ pw,
                                                 const float* __restrict__ pb,
                                                 const float* __restrict__ rw,
                                                 const float* __restrict__ rb,
                                                 float* __restrict__ out_params,
                                                 float* __restrict__ probs,
                                                 float* __restrict__ out_idx,
                                                 int* __restrict__ idx_i,
                                                 int* __restrict__ hist) {
    int r0 = blockIdx.y * 64;
    bool isl = (blockIdx.x == 4);
    int c0 = isl ? 0 : blockIdx.x * 64;

    __shared__ short As[64 * LDSS];
    __shared__ short Bs[64 * LDSS];
    __shared__ short Al[64 * LDSS];   // lo parts, logits tile only
    __shared__ short Bl[64 * LDSS];
    __shared__ int rowcol[64];

    int tid = threadIdx.x;
    int wv = tid >> 6;
    int lane = tid & 63;
    int fm = lane & 15;
    int q = lane >> 4;

    const float* Bsrc = isl ? rw : pw;

    f32x4 acc[4] = {{0.f, 0.f, 0.f, 0.f}, {0.f, 0.f, 0.f, 0.f},
                    {0.f, 0.f, 0.f, 0.f}, {0.f, 0.f, 0.f, 0.f}};

    for (int k0 = 0; k0 < DIM; k0 += 64) {
#pragma unroll
        for (int i = 0; i < 4; ++i) {
            int u = i * 256 + tid;
            int r = u >> 4, g = u & 15;
            float4 v = *(const float4*)&x[(size_t)(r0 + r) * DIM + k0 + g * 4];
            s16x4 h = pk4(v.x, v.y, v.z, v.w);
            *(s16x4*)&As[r * LDSS + g * 4] = h;
            if (isl) {
                s16x4 l = pk4(v.x - bf2f(h[0]), v.y - bf2f(h[1]),
                              v.z - bf2f(h[2]), v.w - bf2f(h[3]));
                *(s16x4*)&Al[r * LDSS + g * 4] = l;
            }
        }
#pragma unroll
        for (int i = 0; i < 4; ++i) {
            int u = i * 256 + tid;
            int c = u >> 4, g = u & 15;
            float4 v = {0.f, 0.f, 0.f, 0.f};
            if (!isl || c < N_TOOLS)
                v = *(const float4*)&Bsrc[(size_t)(c0 + c) * DIM + k0 + g * 4];
            s16x4 h = pk4(v.x, v.y, v.z, v.w);
            *(s16x4*)&Bs[c * LDSS + g * 4] = h;
            if (isl) {
                s16x4 l = pk4(v.x - bf2f(h[0]), v.y - bf2f(h[1]),
                              v.z - bf2f(h[2]), v.w - bf2f(h[3]));
                *(s16x4*)&Bl[c * LDSS + g * 4] = l;
            }
        }
        __syncthreads();

#pragma unroll
        for (int kk = 0; kk < 64; kk += 32) {
            int ao = (wv * 16 + fm) * LDSS + kk + q * 8;
            s16x8 a = *(const s16x8*)&As[ao];
            if (!isl) {
#pragma unroll
                for (int n = 0; n < 4; ++n) {
                    s16x8 b = *(const s16x8*)&Bs[(n * 16 + fm) * LDSS + kk + q * 8];
                    acc[n] = __builtin_amdgcn_mfma_f32_16x16x32_bf16(a, b, acc[n], 0, 0, 0);
                }
            } else {
                s16x8 al = *(const s16x8*)&Al[ao];
#pragma unroll
                for (int n = 0; n < 4; ++n) {
                    int bo = (n * 16 + fm) * LDSS + kk + q * 8;
                    s16x8 b  = *(const s16x8*)&Bs[bo];
                    s16x8 bl = *(const s16x8*)&Bl[bo];
                    acc[n] = __builtin_amdgcn_mfma_f32_16x16x32_bf16(a,  b,  acc[n], 0, 0, 0);
                    acc[n] = __builtin_amdgcn_mfma_f32_16x16x32_bf16(a,  bl, acc[n], 0, 0, 0);
                    acc[n] = __builtin_amdgcn_mfma_f32_16x16x32_bf16(al, b,  acc[n], 0, 0, 0);
                }
            }
        }
        __syncthreads();
    }

    if (!isl) {
        // params epilogue: D layout col=lane&15 (per n-frag), row=q*4+r
        float bias[4];
#pragma unroll
        for (int n = 0; n < 4; ++n) bias[n] = pb[c0 + n * 16 + fm];
#pragma unroll
        for (int r = 0; r < 4; ++r) {
            int row = r0 + wv * 16 + q * 4 + r;
            float* op = out_params + (size_t)row * PARAM_DIM + c0;
#pragma unroll
            for (int n = 0; n < 4; ++n) op[n * 16 + fm] = acc[n][r] + bias[n];
        }
    } else {
        // fused softmax + argmax epilogue. Row's 50 logits live across the 16 lanes
        // sharing this lane's q (fm=0..15) x 4 regs (cols n*16+fm).
        float rbv[4];
#pragma unroll
        for (int n = 0; n < 4; ++n) {
            int c = n * 16 + fm;
            rbv[n] = (c < N_TOOLS) ? rb[c] : 0.f;
        }
#pragma unroll
        for (int rr = 0; rr < 4; ++rr) {
            int row_l = wv * 16 + q * 4 + rr;
            int row = r0 + row_l;
            float v[4];
            float vmax = -INFINITY; int vcol = N_TOOLS;
#pragma unroll
            for (int n = 0; n < 4; ++n) {
                int c = n * 16 + fm;
                v[n] = acc[n][rr] + rbv[n];
                if (c < N_TOOLS && v[n] > vmax) { vmax = v[n]; vcol = c; }
            }
#pragma unroll
            for (int s = 1; s < 16; s <<= 1) {
                float om = __shfl_xor(vmax, s, 64);
                int   oc = __shfl_xor(vcol, s, 64);
                if (om > vmax || (om == vmax && oc < vcol)) { vmax = om; vcol = oc; }
            }
            float e[4]; float esum = 0.f;
#pragma unroll
            for (int n = 0; n < 4; ++n) {
                int c = n * 16 + fm;
                e[n] = (c < N_TOOLS) ? expf(v[n] - vmax) : 0.f;
                esum += e[n];
            }
#pragma unroll
            for (int s = 1; s < 16; s <<= 1) esum += __shfl_xor(esum, s, 64);
            float inv = 1.f / esum;
#pragma unroll
            for (int n = 0; n < 4; ++n) {
                int c = n * 16 + fm;
                if (c < N_TOOLS) probs[(size_t)row * N_TOOLS + c] = e[n] * inv;
            }
            if (fm == 0) {
                out_idx[row] = (float)vcol;
                idx_i[row] = vcol;
                rowcol[row_l] = vcol;
            }
        }
        __syncthreads();   // isl is block-uniform
        if (wv == 0) {
            int myc = rowcol[lane];
            int cnt = 0;
            for (int e2 = 0; e2 < N_TOOLS; ++e2) {
                unsigned long long m = __ballot(myc == e2);
                if (lane == e2) cnt = __popcll(m);
            }
            if (lane < N_TOOLS) hist[blockIdx.y * N_TOOLS + lane] = cnt;
        }
    }
}

// ---------------- scan: expert totals, offsets, block-prefix, batch table ----------------
__global__ void scan_kernel(const int* __restrict__ hist,
                            int* __restrict__ offsets,
                            int* __restrict__ counts,
                            int* __restrict__ phist,
                            int* __restrict__ batch_e,
                            int* __restrict__ batch_m0,
                            int* __restrict__ nb_out) {
    int lane = threadIdx.x;   // 64
    int acc_c = 0;
    if (lane < N_TOOLS) {
#pragma unroll 4
        for (int b = 0; b < N_ROWBLK; ++b) {
            int t = hist[b * N_TOOLS + lane];
            phist[b * N_TOOLS + lane] = acc_c;
            acc_c += t;
        }
    }
    int c = (lane < N_TOOLS) ? acc_c : 0;
    int pre = c;
#pragma unroll
    for (int s = 1; s < 64; s <<= 1) {
        int v = __shfl_up(pre, s, 64);
        if (lane >= s) pre += v;
    }
    int excl = pre - c;
    if (lane < N_TOOLS) { offsets[lane] = excl; counts[lane] = c; }

    int nb_i = (lane < N_TOOLS) ? (c + 63) >> 6 : 0;
    int pre2 = nb_i;
#pragma unroll
    for (int s = 1; s < 64; s <<= 1) {
        int v = __shfl_up(pre2, s, 64);
        if (lane >= s) pre2 += v;
    }
    int bstart = pre2 - nb_i;
    for (int b = 0; b < nb_i; ++b) {
        batch_e[bstart + b] = lane;
        batch_m0[bstart + b] = b * 64;
    }
    if (lane == 63) nb_out[0] = pre2;
}

// ---------------- reorder: deterministic slot per token (no atomics) ----------------
// grid 128 x 64 threads (one wave per row-block)
__global__ void reorder_kernel(const int* __restrict__ idx_i,
                               const int* __restrict__ offsets,
                               const int* __restrict__ phist,
                               int* __restrict__ order) {
    int b = blockIdx.x;
    int lane = threadIdx.x;
    int t = b * 64 + lane;
    int e = idx_i[t];
    unsigned long long lt = (1ull << lane) - 1ull;
    int rank = 0;
    for (int ex = 0; ex < N_TOOLS; ++ex) {
        unsigned long long m = __ballot(e == ex);
        if (e == ex) rank = __popcll(m & lt);
    }
    order[offsets[e] + phist[b * N_TOOLS + e] + rank] = t;
}

// ---------------- adapted: grouped bf16 MFMA GEMM ----------------
// grid (8 col-tiles, MAX_BATCHES), block 256 (4 waves). Tile 64x64, BK=64.
__global__ __launch_bounds__(256) void adapted_mfma(const float* __restrict__ x,
                                                    const float* __restrict__ ew,
                                                    const float* __restrict__ eb,
                                                    const int* __restrict__ order,
                                                    const int* __restrict__ batch_e,
                                                    const int* __restrict__ batch_m0,
                                                    const int* __restrict__ nb_ptr,
                                                    const int* __restrict__ offsets,
                                                    const int* __restrict__ counts,
                                                    float* __restrict__ out) {
    int b = blockIdx.y;
    if (b >= nb_ptr[0]) return;
    int e = batch_e[b];
    int m0 = batch_m0[b];
    int c0 = blockIdx.x * 64;
    int start = offsets[e] + m0;
    int len = counts[e] - m0;
    if (len > 64) len = 64;

    __shared__ short As[64 * LDSS];
    __shared__ short Bs[64 * LDSS];
    __shared__ int toks[64];

    int tid = threadIdx.x;
    if (tid < 64) toks[tid] = (tid < len) ? order[start + tid] : -1;
    __syncthreads();

    int wv = tid >> 6;
    int lane = tid & 63;
    int fm = lane & 15;
    int q = lane >> 4;

    const float* We = ew + (size_t)e * DIM * DIM;

    f32x4 acc[4] = {{0.f, 0.f, 0.f, 0.f}, {0.f, 0.f, 0.f, 0.f},
                    {0.f, 0.f, 0.f, 0.f}, {0.f, 0.f, 0.f, 0.f}};

    for (int k0 = 0; k0 < DIM; k0 += 64) {
#pragma unroll
        for (int i = 0; i < 4; ++i) {
            int u = i * 256 + tid;
            int r = u >> 4, g = u & 15;
            int tok = toks[r];
            float4 v = {0.f, 0.f, 0.f, 0.f};
            if (tok >= 0) v = *(const float4*)&x[(size_t)tok * DIM + k0 + g * 4];
            *(s16x4*)&As[r * LDSS + g * 4] = pk4(v.x, v.y, v.z, v.w);
        }
#pragma unroll
        for (int i = 0; i < 4; ++i) {
            int u = i * 256 + tid;
            int c = u >> 4, g = u & 15;
            float4 v = *(const float4*)&We[(size_t)(c0 + c) * DIM + k0 + g * 4];
            *(s16x4*)&Bs[c * LDSS + g * 4] = pk4(v.x, v.y, v.z, v.w);
        }
        __syncthreads();

#pragma unroll
        for (int kk = 0; kk < 64; kk += 32) {
            s16x8 a = *(const s16x8*)&As[(wv * 16 + fm) * LDSS + kk + q * 8];
#pragma unroll
            for (int n = 0; n < 4; ++n) {
                s16x8 bf = *(const s16x8*)&Bs[(n * 16 + fm) * LDSS + kk + q * 8];
                acc[n] = __builtin_amdgcn_mfma_f32_16x16x32_bf16(a, bf, acc[n], 0, 0, 0);
            }
        }
        __syncthreads();
    }

    float bias[4];
#pragma unroll
    for (int n = 0; n < 4; ++n) bias[n] = eb[(size_t)e * DIM + c0 + n * 16 + fm];

#pragma unroll
    for (int r = 0; r < 4; ++r) {
        int row = wv * 16 + q * 4 + r;
        int tok = toks[row];
        if (tok < 0) continue;
        float* op = out + (size_t)tok * DIM + c0;
#pragma unroll
        for (int n = 0; n < 4; ++n) op[n * 16 + fm] = acc[n][r] + bias[n];
    }
}

extern "C" void kernel_launch(void* const* d_in, const int* in_sizes, int n_in,
                              void* d_out, int out_size, void* d_ws, size_t ws_size,
                              hipStream_t stream) {
    const float* x        = (const float*)d_in[0];
    const float* router_w = (const float*)d_in[1];
    const float* router_b = (const float*)d_in[2];
    const float* expert_w = (const float*)d_in[3];
    const float* expert_b = (const float*)d_in[4];
    const float* param_w  = (const float*)d_in[5];
    const float* param_b  = (const float*)d_in[6];

    float* out = (float*)d_out;
    float* out_idx     = out;                                  // 8192
    float* out_probs   = out + N_TOKENS;                       // 409600
    float* out_adapted = out + N_TOKENS + N_TOKENS * N_TOOLS;  // 4194304
    float* out_params  = out_adapted + (size_t)N_TOKENS * DIM; // 2097152

    int* ws = (int*)d_ws;
    int* ws_idx     = ws + WS_IDX;
    int* ws_hist    = ws + WS_HIST;
    int* ws_phist   = ws + WS_PHIST;
    int* ws_offsets = ws + WS_OFFSETS;
    int* ws_counts  = ws + WS_COUNTS;
    int* ws_order   = ws + WS_ORDER;
    int* ws_be      = ws + WS_BE;
    int* ws_bm0     = ws + WS_BM0;
    int* ws_nb      = ws + WS_NB;

    head_mfma<<<dim3(5, N_ROWBLK), 256, 0, stream>>>(x, param_w, param_b,
                                                     router_w, router_b,
                                                     out_params, out_probs,
                                                     out_idx, ws_idx, ws_hist);

    scan_kernel<<<1, 64, 0, stream>>>(ws_hist, ws_offsets, ws_counts, ws_phist,
                                      ws_be, ws_bm0, ws_nb);

    reorder_kernel<<<N_ROWBLK, 64, 0, stream>>>(ws_idx, ws_offsets, ws_phist, ws_order);

    adapted_mfma<<<dim3(8, MAX_BATCHES), 256, 0, stream>>>(x, expert_w, expert_b,
                                                           ws_order, ws_be, ws_bm0, ws_nb,
                                                           ws_offsets, ws_counts, out_adapted);
}

// Round 5
// 155.832 us; speedup vs baseline: 4.4221x; 1.1338x over previous
//
#include <hip/hip_runtime.h>
#include <hip/hip_bf16.h>
#include <math.h>

#define N_TOKENS 8192
#define DIM      512
#define N_TOOLS  50
#define PARAM_DIM 256
#define N_ROWBLK (N_TOKENS / 64)   // 128
#define MAX_BATCHES 192
#define LDSS 72   // LDS inner stride in bf16 elems (144 B -> 2-way bank aliasing max, free)

typedef float  f32x4 __attribute__((ext_vector_type(4)));
typedef short  s16x8 __attribute__((ext_vector_type(8)));
typedef short  s16x4 __attribute__((ext_vector_type(4)));

// ---- workspace layout (ints) ----
#define WS_IDX     0        // 8192  token -> expert
#define WS_HIST    8192     // 128*50 per-rowblock histograms
#define WS_PHIST   14592    // 128*50 exclusive block-prefix per expert
#define WS_OFFSETS 20992    // 64
#define WS_COUNTS  21056    // 64
#define WS_ORDER   21120    // 8192
#define WS_BE      29312    // 192
#define WS_BM0     29504    // 192
#define WS_NB      29696    // 1
#define WS_XH      32768    // 8192*512 bf16 = 2,097,152 ints
#define WS_XL      2130944  // 8192*512 bf16

__device__ inline float bf2f(short s) {
    return __uint_as_float(((unsigned)(unsigned short)s) << 16);
}

__device__ inline s16x4 pk4(float a, float b, float c, float d) {
    __hip_bfloat162 p0 = __float22bfloat162_rn(make_float2(a, b));
    __hip_bfloat162 p1 = __float22bfloat162_rn(make_float2(c, d));
    union { __hip_bfloat162 h; short2 s; } u0, u1;
    u0.h = p0; u1.h = p1;
    s16x4 r; r[0] = u0.s.x; r[1] = u0.s.y; r[2] = u1.s.x; r[3] = u1.s.y;
    return r;
}

// ---------------- pre-convert x to bf16 hi + lo ----------------
__global__ __launch_bounds__(256) void cvt_x_kernel(const float* __restrict__ x,
                                                    short* __restrict__ xh,
                                                    short* __restrict__ xl) {
    size_t i = (size_t)(blockIdx.x * 256 + threadIdx.x) * 4;
    float4 v = *(const float4*)&x[i];
    s16x4 h = pk4(v.x, v.y, v.z, v.w);
    s16x4 l = pk4(v.x - bf2f(h[0]), v.y - bf2f(h[1]),
                  v.z - bf2f(h[2]), v.w - bf2f(h[3]));
    *(s16x4*)&xh[i] = h;
    *(s16x4*)&xl[i] = l;
}

// ---------------- fused head: params (tiles 0-3) + logits/softmax/argmax (tile 4) ----------------
// grid (5, 128), block 256 (4 waves). Tile 64x64, BK=64, register-prefetch pipeline.
__global__ __launch_bounds__(256) void head_mfma(const short* __restrict__ xh,
                                                 const short* __restrict__ xl,
                                                 const float* __restrict__ pw,
                                                 const float* __restrict__ pb,
                                                 const float* __restrict__ rw,
                                                 const float* __restrict__ rb,
                                                 float* __restrict__ out_params,
                                                 float* __restrict__ probs,
                                                 float* __restrict__ out_idx,
                                                 int* __restrict__ idx_i,
                                                 int* __restrict__ hist) {
    int r0 = blockIdx.y * 64;
    bool isl = (blockIdx.x == 4);
    int c0 = isl ? 0 : blockIdx.x * 64;

    __shared__ short As[64 * LDSS];
    __shared__ short Bs[64 * LDSS];
    __shared__ short Al[64 * LDSS];   // lo parts, logits tile only
    __shared__ short Bl[64 * LDSS];
    __shared__ int rowcol[64];

    int tid = threadIdx.x;
    int wv = tid >> 6;
    int lane = tid & 63;
    int fm = lane & 15;
    int q = lane >> 4;

    const float* Bsrc = isl ? rw : pw;

    // per-thread constant staging coordinates
    int ar0 = tid >> 3, ag = tid & 7;          // A chunk 0: row ar0, 16B granule ag
    int ar1 = ar0 + 32;                        // A chunk 1
    const short* aptr0 = xh + (size_t)(r0 + ar0) * DIM + ag * 8;
    const short* aptr1 = xh + (size_t)(r0 + ar1) * DIM + ag * 8;
    const short* alptr0 = xl + (size_t)(r0 + ar0) * DIM + ag * 8;
    const short* alptr1 = xl + (size_t)(r0 + ar1) * DIM + ag * 8;
    int bc[4], bg[4];
    const float* bptr[4];
#pragma unroll
    for (int i = 0; i < 4; ++i) {
        int u = i * 256 + tid;
        bc[i] = u >> 4; bg[i] = u & 15;
        bptr[i] = Bsrc + (size_t)(c0 + bc[i]) * DIM + bg[i] * 4;
    }

    f32x4 acc[4] = {{0.f, 0.f, 0.f, 0.f}, {0.f, 0.f, 0.f, 0.f},
                    {0.f, 0.f, 0.f, 0.f}, {0.f, 0.f, 0.f, 0.f}};

    // prologue prefetch (k0 = 0)
    s16x8 apre0, apre1, alpre0, alpre1;
    float4 bpre[4];
    apre0 = *(const s16x8*)aptr0;
    apre1 = *(const s16x8*)aptr1;
    if (isl) { alpre0 = *(const s16x8*)alptr0; alpre1 = *(const s16x8*)alptr1; }
#pragma unroll
    for (int i = 0; i < 4; ++i) {
        float4 v = {0.f, 0.f, 0.f, 0.f};
        if (!isl || bc[i] < N_TOOLS) v = *(const float4*)bptr[i];
        bpre[i] = v;
    }

    for (int k0 = 0; k0 < DIM; k0 += 64) {
        // store current prefetch into LDS
        *(s16x8*)&As[ar0 * LDSS + ag * 8] = apre0;
        *(s16x8*)&As[ar1 * LDSS + ag * 8] = apre1;
        if (isl) {
            *(s16x8*)&Al[ar0 * LDSS + ag * 8] = alpre0;
            *(s16x8*)&Al[ar1 * LDSS + ag * 8] = alpre1;
        }
#pragma unroll
        for (int i = 0; i < 4; ++i) {
            float4 v = bpre[i];
            s16x4 h = pk4(v.x, v.y, v.z, v.w);
            *(s16x4*)&Bs[bc[i] * LDSS + bg[i] * 4] = h;
            if (isl) {
                s16x4 l = pk4(v.x - bf2f(h[0]), v.y - bf2f(h[1]),
                              v.z - bf2f(h[2]), v.w - bf2f(h[3]));
                *(s16x4*)&Bl[bc[i] * LDSS + bg[i] * 4] = l;
            }
        }
        __syncthreads();

        // prefetch next tile (overlaps the MFMA section below)
        int kn = k0 + 64;
        if (kn < DIM) {
            apre0 = *(const s16x8*)(aptr0 + kn);
            apre1 = *(const s16x8*)(aptr1 + kn);
            if (isl) {
                alpre0 = *(const s16x8*)(alptr0 + kn);
                alpre1 = *(const s16x8*)(alptr1 + kn);
            }
#pragma unroll
            for (int i = 0; i < 4; ++i) {
                float4 v = {0.f, 0.f, 0.f, 0.f};
                if (!isl || bc[i] < N_TOOLS) v = *(const float4*)(bptr[i] + kn);
                bpre[i] = v;
            }
        }

#pragma unroll
        for (int kk = 0; kk < 64; kk += 32) {
            int ao = (wv * 16 + fm) * LDSS + kk + q * 8;
            s16x8 a = *(const s16x8*)&As[ao];
            if (!isl) {
#pragma unroll
                for (int n = 0; n < 4; ++n) {
                    s16x8 b = *(const s16x8*)&Bs[(n * 16 + fm) * LDSS + kk + q * 8];
                    acc[n] = __builtin_amdgcn_mfma_f32_16x16x32_bf16(a, b, acc[n], 0, 0, 0);
                }
            } else {
                s16x8 al = *(const s16x8*)&Al[ao];
#pragma unroll
                for (int n = 0; n < 4; ++n) {
                    int bo = (n * 16 + fm) * LDSS + kk + q * 8;
                    s16x8 b  = *(const s16x8*)&Bs[bo];
                    s16x8 bl = *(const s16x8*)&Bl[bo];
                    acc[n] = __builtin_amdgcn_mfma_f32_16x16x32_bf16(a,  b,  acc[n], 0, 0, 0);
                    acc[n] = __builtin_amdgcn_mfma_f32_16x16x32_bf16(a,  bl, acc[n], 0, 0, 0);
                    acc[n] = __builtin_amdgcn_mfma_f32_16x16x32_bf16(al, b,  acc[n], 0, 0, 0);
                }
            }
        }
        __syncthreads();
    }

    if (!isl) {
        float bias[4];
#pragma unroll
        for (int n = 0; n < 4; ++n) bias[n] = pb[c0 + n * 16 + fm];
#pragma unroll
        for (int r = 0; r < 4; ++r) {
            int row = r0 + wv * 16 + q * 4 + r;
            float* op = out_params + (size_t)row * PARAM_DIM + c0;
#pragma unroll
            for (int n = 0; n < 4; ++n) op[n * 16 + fm] = acc[n][r] + bias[n];
        }
    } else {
        float rbv[4];
#pragma unroll
        for (int n = 0; n < 4; ++n) {
            int c = n * 16 + fm;
            rbv[n] = (c < N_TOOLS) ? rb[c] : 0.f;
        }
#pragma unroll
        for (int rr = 0; rr < 4; ++rr) {
            int row_l = wv * 16 + q * 4 + rr;
            int row = r0 + row_l;
            float v[4];
            float vmax = -INFINITY; int vcol = N_TOOLS;
#pragma unroll
            for (int n = 0; n < 4; ++n) {
                int c = n * 16 + fm;
                v[n] = acc[n][rr] + rbv[n];
                if (c < N_TOOLS && v[n] > vmax) { vmax = v[n]; vcol = c; }
            }
#pragma unroll
            for (int s = 1; s < 16; s <<= 1) {
                float om = __shfl_xor(vmax, s, 64);
                int   oc = __shfl_xor(vcol, s, 64);
                if (om > vmax || (om == vmax && oc < vcol)) { vmax = om; vcol = oc; }
            }
            float e[4]; float esum = 0.f;
#pragma unroll
            for (int n = 0; n < 4; ++n) {
                int c = n * 16 + fm;
                e[n] = (c < N_TOOLS) ? expf(v[n] - vmax) : 0.f;
                esum += e[n];
            }
#pragma unroll
            for (int s = 1; s < 16; s <<= 1) esum += __shfl_xor(esum, s, 64);
            float inv = 1.f / esum;
#pragma unroll
            for (int n = 0; n < 4; ++n) {
                int c = n * 16 + fm;
                if (c < N_TOOLS) probs[(size_t)row * N_TOOLS + c] = e[n] * inv;
            }
            if (fm == 0) {
                out_idx[row] = (float)vcol;
                idx_i[row] = vcol;
                rowcol[row_l] = vcol;
            }
        }
        __syncthreads();   // isl is block-uniform
        if (wv == 0) {
            int myc = rowcol[lane];
            int cnt = 0;
            for (int e2 = 0; e2 < N_TOOLS; ++e2) {
                unsigned long long m = __ballot(myc == e2);
                if (lane == e2) cnt = __popcll(m);
            }
            if (lane < N_TOOLS) hist[blockIdx.y * N_TOOLS + lane] = cnt;
        }
    }
}

// ---------------- scan stage 1: per-expert block-prefix (50 blocks x 1 wave) ----------------
__global__ void scan1_kernel(const int* __restrict__ hist,
                             int* __restrict__ phist,
                             int* __restrict__ counts) {
    int e = blockIdx.x;      // expert
    int l = threadIdx.x;     // 64
    int v0 = hist[l * N_TOOLS + e];
    int v1 = hist[(64 + l) * N_TOOLS + e];
    int s0 = v0;
#pragma unroll
    for (int s = 1; s < 64; s <<= 1) {
        int t = __shfl_up(s0, s, 64);
        if (l >= s) s0 += t;
    }
    int tot0 = __shfl(s0, 63, 64);
    int s1 = v1;
#pragma unroll
    for (int s = 1; s < 64; s <<= 1) {
        int t = __shfl_up(s1, s, 64);
        if (l >= s) s1 += t;
    }
    s1 += tot0;
    phist[l * N_TOOLS + e] = s0 - v0;
    phist[(64 + l) * N_TOOLS + e] = s1 - v1;
    if (l == 63) counts[e] = s1;
}

// ---------------- scan stage 2: offsets + batch table (1 wave) ----------------
__global__ void scan2_kernel(const int* __restrict__ counts,
                             int* __restrict__ offsets,
                             int* __restrict__ batch_e,
                             int* __restrict__ batch_m0,
                             int* __restrict__ nb_out) {
    int lane = threadIdx.x;   // 64
    int c = (lane < N_TOOLS) ? counts[lane] : 0;
    int pre = c;
#pragma unroll
    for (int s = 1; s < 64; s <<= 1) {
        int v = __shfl_up(pre, s, 64);
        if (lane >= s) pre += v;
    }
    if (lane < N_TOOLS) offsets[lane] = pre - c;

    int nb_i = (lane < N_TOOLS) ? (c + 63) >> 6 : 0;
    int pre2 = nb_i;
#pragma unroll
    for (int s = 1; s < 64; s <<= 1) {
        int v = __shfl_up(pre2, s, 64);
        if (lane >= s) pre2 += v;
    }
    int bstart = pre2 - nb_i;
    for (int b = 0; b < nb_i; ++b) {
        batch_e[bstart + b] = lane;
        batch_m0[bstart + b] = b * 64;
    }
    if (lane == 63) nb_out[0] = pre2;
}

// ---------------- reorder: deterministic slot per token (no atomics) ----------------
__global__ void reorder_kernel(const int* __restrict__ idx_i,
                               const int* __restrict__ offsets,
                               const int* __restrict__ phist,
                               int* __restrict__ order) {
    int b = blockIdx.x;
    int lane = threadIdx.x;
    int t = b * 64 + lane;
    int e = idx_i[t];
    unsigned long long lt = (1ull << lane) - 1ull;
    int rank = 0;
    for (int ex = 0; ex < N_TOOLS; ++ex) {
        unsigned long long m = __ballot(e == ex);
        if (e == ex) rank = __popcll(m & lt);
    }
    order[offsets[e] + phist[b * N_TOOLS + e] + rank] = t;
}

// ---------------- adapted: grouped bf16 MFMA GEMM, register-prefetch pipeline ----------------
// grid (8 col-tiles, MAX_BATCHES), block 256 (4 waves). Tile 64x64, BK=64.
__global__ __launch_bounds__(256) void adapted_mfma(const short* __restrict__ xh,
                                                    const float* __restrict__ ew,
                                                    const float* __restrict__ eb,
                                                    const int* __restrict__ order,
                                                    const int* __restrict__ batch_e,
                                                    const int* __restrict__ batch_m0,
                                                    const int* __restrict__ nb_ptr,
                                                    const int* __restrict__ offsets,
                                                    const int* __restrict__ counts,
                                                    float* __restrict__ out) {
    int b = blockIdx.y;
    if (b >= nb_ptr[0]) return;
    int e = batch_e[b];
    int m0 = batch_m0[b];
    int c0 = blockIdx.x * 64;
    int start = offsets[e] + m0;
    int len = counts[e] - m0;
    if (len > 64) len = 64;

    __shared__ short As[64 * LDSS];
    __shared__ short Bs[64 * LDSS];
    __shared__ int toks[64];

    int tid = threadIdx.x;
    if (tid < 64) toks[tid] = (tid < len) ? order[start + tid] : -1;
    __syncthreads();

    int wv = tid >> 6;
    int lane = tid & 63;
    int fm = lane & 15;
    int q = lane >> 4;

    const float* We = ew + (size_t)e * DIM * DIM;

    // constant per-thread staging coordinates
    int ar0 = tid >> 3, ag = tid & 7;
    int ar1 = ar0 + 32;
    int tok0 = toks[ar0], tok1 = toks[ar1];
    const short* aptr0 = (tok0 >= 0) ? xh + (size_t)tok0 * DIM + ag * 8 : nullptr;
    const short* aptr1 = (tok1 >= 0) ? xh + (size_t)tok1 * DIM + ag * 8 : nullptr;
    int bc[4], bg[4];
    const float* bptr[4];
#pragma unroll
    for (int i = 0; i < 4; ++i) {
        int u = i * 256 + tid;
        bc[i] = u >> 4; bg[i] = u & 15;
        bptr[i] = We + (size_t)(c0 + bc[i]) * DIM + bg[i] * 4;
    }

    f32x4 acc[4] = {{0.f, 0.f, 0.f, 0.f}, {0.f, 0.f, 0.f, 0.f},
                    {0.f, 0.f, 0.f, 0.f}, {0.f, 0.f, 0.f, 0.f}};

    const s16x8 z8 = {0, 0, 0, 0, 0, 0, 0, 0};
    s16x8 apre0 = aptr0 ? *(const s16x8*)aptr0 : z8;
    s16x8 apre1 = aptr1 ? *(const s16x8*)aptr1 : z8;
    float4 bpre[4];
#pragma unroll
    for (int i = 0; i < 4; ++i) bpre[i] = *(const float4*)bptr[i];

    for (int k0 = 0; k0 < DIM; k0 += 64) {
        *(s16x8*)&As[ar0 * LDSS + ag * 8] = apre0;
        *(s16x8*)&As[ar1 * LDSS + ag * 8] = apre1;
#pragma unroll
        for (int i = 0; i < 4; ++i) {
            float4 v = bpre[i];
            *(s16x4*)&Bs[bc[i] * LDSS + bg[i] * 4] = pk4(v.x, v.y, v.z, v.w);
        }
        __syncthreads();

        int kn = k0 + 64;
        if (kn < DIM) {
            apre0 = aptr0 ? *(const s16x8*)(aptr0 + kn) : z8;
            apre1 = aptr1 ? *(const s16x8*)(aptr1 + kn) : z8;
#pragma unroll
            for (int i = 0; i < 4; ++i) bpre[i] = *(const float4*)(bptr[i] + kn);
        }

#pragma unroll
        for (int kk = 0; kk < 64; kk += 32) {
            s16x8 a = *(const s16x8*)&As[(wv * 16 + fm) * LDSS + kk + q * 8];
#pragma unroll
            for (int n = 0; n < 4; ++n) {
                s16x8 bf = *(const s16x8*)&Bs[(n * 16 + fm) * LDSS + kk + q * 8];
                acc[n] = __builtin_amdgcn_mfma_f32_16x16x32_bf16(a, bf, acc[n], 0, 0, 0);
            }
        }
        __syncthreads();
    }

    float bias[4];
#pragma unroll
    for (int n = 0; n < 4; ++n) bias[n] = eb[(size_t)e * DIM + c0 + n * 16 + fm];

#pragma unroll
    for (int r = 0; r < 4; ++r) {
        int row = wv * 16 + q * 4 + r;
        int tok = toks[row];
        if (tok < 0) continue;
        float* op = out + (size_t)tok * DIM + c0;
#pragma unroll
        for (int n = 0; n < 4; ++n) op[n * 16 + fm] = acc[n][r] + bias[n];
    }
}

extern "C" void kernel_launch(void* const* d_in, const int* in_sizes, int n_in,
                              void* d_out, int out_size, void* d_ws, size_t ws_size,
                              hipStream_t stream) {
    const float* x        = (const float*)d_in[0];
    const float* router_w = (const float*)d_in[1];
    const float* router_b = (const float*)d_in[2];
    const float* expert_w = (const float*)d_in[3];
    const float* expert_b = (const float*)d_in[4];
    const float* param_w  = (const float*)d_in[5];
    const float* param_b  = (const float*)d_in[6];

    float* out = (float*)d_out;
    float* out_idx     = out;                                  // 8192
    float* out_probs   = out + N_TOKENS;                       // 409600
    float* out_adapted = out + N_TOKENS + N_TOKENS * N_TOOLS;  // 4194304
    float* out_params  = out_adapted + (size_t)N_TOKENS * DIM; // 2097152

    int* ws = (int*)d_ws;
    int* ws_idx     = ws + WS_IDX;
    int* ws_hist    = ws + WS_HIST;
    int* ws_phist   = ws + WS_PHIST;
    int* ws_offsets = ws + WS_OFFSETS;
    int* ws_counts  = ws + WS_COUNTS;
    int* ws_order   = ws + WS_ORDER;
    int* ws_be      = ws + WS_BE;
    int* ws_bm0     = ws + WS_BM0;
    int* ws_nb      = ws + WS_NB;
    short* ws_xh    = (short*)(ws + WS_XH);
    short* ws_xl    = (short*)(ws + WS_XL);

    cvt_x_kernel<<<N_TOKENS * DIM / 4 / 256, 256, 0, stream>>>(x, ws_xh, ws_xl);

    head_mfma<<<dim3(5, N_ROWBLK), 256, 0, stream>>>(ws_xh, ws_xl, param_w, param_b,
                                                     router_w, router_b,
                                                     out_params, out_probs,
                                                     out_idx, ws_idx, ws_hist);

    scan1_kernel<<<N_TOOLS, 64, 0, stream>>>(ws_hist, ws_phist, ws_counts);

    scan2_kernel<<<1, 64, 0, stream>>>(ws_counts, ws_offsets, ws_be, ws_bm0, ws_nb);

    reorder_kernel<<<N_ROWBLK, 64, 0, stream>>>(ws_idx, ws_offsets, ws_phist, ws_order);

    adapted_mfma<<<dim3(8, MAX_BATCHES), 256, 0, stream>>>(ws_xh, expert_w, expert_b,
                                                           ws_order, ws_be, ws_bm0, ws_nb,
                                                           ws_offsets, ws_counts, out_adapted);
}